// Round 2
// baseline (155.855 us; speedup 1.0000x reference)
//
#include <hip/hip_runtime.h>
#include <hip/hip_bf16.h>

// NT-Xent loss, N=4096, Z=128, T=0.5.
// Pipeline:
//  k_normalize: row-normalize z1/z2 (fp32), quantize to bf16 scaled by
//               QS = sqrt(2*log2(e)) so that the GEMM accumulator is already
//               2*log2(e)*sim -> epilogue is a bare exp2. Also zeroes denom
//               (blocks 0..31) and writes exact fp32 pair-cosines pos[4096].
//  k_simsum:    denom[i] = sum_{j != i} exp(2 * sim_ij)  via bf16 MFMA GEMM
//               with fused exp2 + row-sum epilogue. No LDS, no barriers;
//               full-K A-frags persist in registers (K=128 = 4 MFMA steps).
//               acc tile 4x2 (32 AGPR) to fit 3 waves/SIMD.
//  k_finish:    out = (sum_i log denom_i - 4 * sum_p pos_p) / 8192

#define N_PAIRS 4096
#define ZDIM    128
#define NROWS   8192
// sqrt(2 * log2(e)) : folds the 1/T=2 and the exp->exp2 conversion into the
// bf16 quantization so the epilogue needs no multiply.
#define QS 1.6986437717f

typedef __bf16 bf16x8 __attribute__((ext_vector_type(8)));
typedef float  floatx4 __attribute__((ext_vector_type(4)));

__global__ __launch_bounds__(256) void k_normalize(
    const float* __restrict__ z1, const float* __restrict__ z2,
    __hip_bfloat16* __restrict__ nreps, float* __restrict__ pos,
    float* __restrict__ denom)
{
    // fold denom zeroing into this kernel (grid = 1024 blocks; need 32)
    const int zi = blockIdx.x * 256 + threadIdx.x;
    if (zi < NROWS) denom[zi] = 0.0f;

    const int w = threadIdx.x >> 6;
    const int lane = threadIdx.x & 63;
    const int p = blockIdx.x * 4 + w;            // pair index, < 4096
    const float2 a = ((const float2*)(z1 + (size_t)p * ZDIM))[lane];
    const float2 b = ((const float2*)(z2 + (size_t)p * ZDIM))[lane];
    float s1 = a.x * a.x + a.y * a.y;
    float s2 = b.x * b.x + b.y * b.y;
    float d  = a.x * b.x + a.y * b.y;
    #pragma unroll
    for (int off = 1; off < 64; off <<= 1) {
        s1 += __shfl_xor(s1, off, 64);
        s2 += __shfl_xor(s2, off, 64);
        d  += __shfl_xor(d,  off, 64);
    }
    const float n1 = fmaxf(sqrtf(s1), 1e-8f);
    const float n2 = fmaxf(sqrtf(s2), 1e-8f);
    const float i1 = 1.0f / n1, i2 = 1.0f / n2;
    const float q1 = i1 * QS, q2 = i2 * QS;
    float2 na; na.x = a.x * q1; na.y = a.y * q1;
    float2 nb; nb.x = b.x * q2; nb.y = b.y * q2;
    ((__hip_bfloat162*)(nreps + (size_t)p * ZDIM))[lane] = __float22bfloat162_rn(na);
    ((__hip_bfloat162*)(nreps + (size_t)(p + N_PAIRS) * ZDIM))[lane] = __float22bfloat162_rn(nb);
    if (lane == 0) pos[p] = d * i1 * i2;
}

// Block: 256 thr = 4 waves in 2x2; block tile = 128 rows x 64 cols, swept
// over 8 column steps (512-col slab). grid = 64 row-tiles * 16 col-slabs =
// 1024 blocks. acc 4x2 (32 AGPR) + afrag 64 VGPR -> ~145 regs, 3 waves/SIMD.
__global__ __launch_bounds__(256, 3) void k_simsum(
    const __hip_bfloat16* __restrict__ nreps, float* __restrict__ denom)
{
    const int tid  = threadIdx.x;
    const int lane = tid & 63;
    const int w    = tid >> 6;
    const int wr   = w >> 1, wc = w & 1;
    const int rt   = blockIdx.x >> 4;   // row tile [0,64)
    const int cs   = blockIdx.x & 15;   // col slab [0,16)
    const int q    = lane >> 4;         // quad 0..3 (selects k-chunk of 8)
    const int l16  = lane & 15;

    // ---- persistent A fragments: wave's 64 rows x full K=128 (64 VGPRs) ----
    // A-operand layout: A[m = lane&15][k = q*8 + j]
    const int arowb = rt * 128 + wr * 64;                // + mt*16 (+ l16)
    const __hip_bfloat16* Abase = nreps + (size_t)(arowb + l16) * ZDIM + q * 8;
    bf16x8 afrag[4][4];
    #pragma unroll
    for (int mt = 0; mt < 4; ++mt)
        #pragma unroll
        for (int ks = 0; ks < 4; ++ks)
            afrag[mt][ks] = *(const bf16x8*)(Abase + mt * 16 * ZDIM + ks * 32);

    float rowsum[4][4];
    #pragma unroll
    for (int mt = 0; mt < 4; ++mt)
        #pragma unroll
        for (int r = 0; r < 4; ++r) rowsum[mt][r] = 0.0f;

    for (int it = 0; it < 8; ++it) {
        floatx4 acc[4][2];
        #pragma unroll
        for (int mt = 0; mt < 4; ++mt)
            #pragma unroll
            for (int nt = 0; nt < 2; ++nt) {
                acc[mt][nt].x = 0.f; acc[mt][nt].y = 0.f;
                acc[mt][nt].z = 0.f; acc[mt][nt].w = 0.f;
            }
        // B-operand layout: B[k = q*8 + j][n = lane&15]; row-major source,
        // so B-frag load pattern is identical to A-frag (sim = A * A^T).
        const int colb = cs * 512 + it * 64 + wc * 32;   // + nt*16 (+ l16)
        const __hip_bfloat16* Bbase = nreps + (size_t)(colb + l16) * ZDIM + q * 8;
        #pragma unroll
        for (int ks = 0; ks < 4; ++ks) {
            bf16x8 bfrag[2];
            #pragma unroll
            for (int nt = 0; nt < 2; ++nt)
                bfrag[nt] = *(const bf16x8*)(Bbase + nt * 16 * ZDIM + ks * 32);
            #pragma unroll
            for (int mt = 0; mt < 4; ++mt)
                #pragma unroll
                for (int nt = 0; nt < 2; ++nt)
                    acc[mt][nt] = __builtin_amdgcn_mfma_f32_16x16x32_bf16(
                        afrag[mt][ks], bfrag[nt], acc[mt][nt], 0, 0, 0);
        }
        // ---- fused epilogue: bare exp2 + row-sum ----
        // C/D layout: col = lane&15, row = q*4 + reg  (m89/m91 verified)
        // Diagonal can only appear when a 16x16 C-tile's row-base == col-base
        // (wave-uniform compare) -> masked path is rare.
        #pragma unroll
        for (int mt = 0; mt < 4; ++mt) {
            const int rowtb = arowb + mt * 16;
            #pragma unroll
            for (int nt = 0; nt < 2; ++nt) {
                const int coltb = colb + nt * 16;
                if (rowtb == coltb) {
                    #pragma unroll
                    for (int r = 0; r < 4; ++r) {
                        const float e = __builtin_amdgcn_exp2f(acc[mt][nt][r]);
                        rowsum[mt][r] += (l16 == q * 4 + r) ? 0.0f : e;
                    }
                } else {
                    #pragma unroll
                    for (int r = 0; r < 4; ++r)
                        rowsum[mt][r] += __builtin_amdgcn_exp2f(acc[mt][nt][r]);
                }
            }
        }
    }

    // reduce across the 16 lanes holding the same row (cols 0..15 of frag)
    #pragma unroll
    for (int mt = 0; mt < 4; ++mt)
        #pragma unroll
        for (int r = 0; r < 4; ++r) {
            float s = rowsum[mt][r];
            s += __shfl_xor(s, 1, 64);
            s += __shfl_xor(s, 2, 64);
            s += __shfl_xor(s, 4, 64);
            s += __shfl_xor(s, 8, 64);
            rowsum[mt][r] = s;
        }
    if (l16 == 0) {
        #pragma unroll
        for (int mt = 0; mt < 4; ++mt)
            #pragma unroll
            for (int r = 0; r < 4; ++r) {
                const int grow = arowb + mt * 16 + q * 4 + r;
                atomicAdd(&denom[grow], rowsum[mt][r]);
            }
    }
}

__global__ __launch_bounds__(1024) void k_finish(
    const float* __restrict__ denom, const float* __restrict__ pos,
    float* __restrict__ out)
{
    __shared__ float red[1024];
    const int t = threadIdx.x;
    float s = 0.0f;
    for (int i = t; i < NROWS; i += 1024) s += __logf(denom[i]);
    float p = 0.0f;
    for (int i = t; i < N_PAIRS; i += 1024) p += pos[i];
    red[t] = s - 4.0f * p;   // sum_i pos_i/T over 2N rows = 4 * sum_p cos_p
    __syncthreads();
    for (int off = 512; off > 0; off >>= 1) {
        if (t < off) red[t] += red[t + off];
        __syncthreads();
    }
    if (t == 0) out[0] = red[0] / (float)NROWS;
}

extern "C" void kernel_launch(void* const* d_in, const int* in_sizes, int n_in,
                              void* d_out, int out_size, void* d_ws, size_t ws_size,
                              hipStream_t stream) {
    const float* z1 = (const float*)d_in[0];
    const float* z2 = (const float*)d_in[1];
    float* out = (float*)d_out;

    char* ws = (char*)d_ws;
    __hip_bfloat16* nreps = (__hip_bfloat16*)ws;               // 2 MB
    float* denom = (float*)(ws + (size_t)NROWS * ZDIM * 2);    // 32 KB
    float* pos   = denom + NROWS;                              // 16 KB

    k_normalize<<<N_PAIRS / 4, 256, 0, stream>>>(z1, z2, nreps, pos, denom);
    k_simsum<<<1024, 256, 0, stream>>>(nreps, denom);
    k_finish<<<1, 1024, 0, stream>>>(denom, pos, out);
}

// Round 3
// 126.472 us; speedup vs baseline: 1.2323x; 1.2323x over previous
//
#include <hip/hip_runtime.h>
#include <hip/hip_bf16.h>

// NT-Xent loss, N=4096, Z=128, T=0.5.
// Pipeline:
//  k_normalize: row-normalize z1/z2 (fp32), quantize to bf16 scaled by
//               QS = sqrt(2*log2(e)) so the GEMM accumulator is already
//               2*log2(e)*sim -> epilogue is a bare exp2. Also zeroes denom.
//               Exact fp32 pair-cosines pos[4096].
//  k_simsum:    denom[i] = sum_{j != i} exp(2*sim_ij) via bf16 MFMA GEMM with
//               fused exp2 + row-sum epilogue. No LDS, no barriers. Per-wave
//               footprint kept ~110 unified regs (afrag[2][4]=32, acc[2][4]=32,
//               rowsum 8, bfrag 16 transient) so 4 waves/SIMD fit WITHOUT a
//               forced min-waves bound (round 2: forcing (256,3) spilled
//               afrag to scratch -> 170 MB scratch writes, 2.3x regression).
//  k_finish:    out = (sum_i log denom_i - 4 * sum_p pos_p) / 8192

#define N_PAIRS 4096
#define ZDIM    128
#define NROWS   8192
// sqrt(2 * log2(e)) : folds 1/T=2 and exp->exp2 into the quantization.
#define QS 1.6986437717f

typedef __bf16 bf16x8 __attribute__((ext_vector_type(8)));
typedef float  floatx4 __attribute__((ext_vector_type(4)));

__global__ __launch_bounds__(256) void k_normalize(
    const float* __restrict__ z1, const float* __restrict__ z2,
    __hip_bfloat16* __restrict__ nreps, float* __restrict__ pos,
    float* __restrict__ denom)
{
    const int zi = blockIdx.x * 256 + threadIdx.x;   // grid 1024 blocks; 32 zero denom
    if (zi < NROWS) denom[zi] = 0.0f;

    const int w = threadIdx.x >> 6;
    const int lane = threadIdx.x & 63;
    const int p = blockIdx.x * 4 + w;            // pair index, < 4096
    const float2 a = ((const float2*)(z1 + (size_t)p * ZDIM))[lane];
    const float2 b = ((const float2*)(z2 + (size_t)p * ZDIM))[lane];
    float s1 = a.x * a.x + a.y * a.y;
    float s2 = b.x * b.x + b.y * b.y;
    float d  = a.x * b.x + a.y * b.y;
    #pragma unroll
    for (int off = 1; off < 64; off <<= 1) {
        s1 += __shfl_xor(s1, off, 64);
        s2 += __shfl_xor(s2, off, 64);
        d  += __shfl_xor(d,  off, 64);
    }
    const float n1 = fmaxf(sqrtf(s1), 1e-8f);
    const float n2 = fmaxf(sqrtf(s2), 1e-8f);
    const float i1 = 1.0f / n1, i2 = 1.0f / n2;
    const float q1 = i1 * QS, q2 = i2 * QS;
    float2 na; na.x = a.x * q1; na.y = a.y * q1;
    float2 nb; nb.x = b.x * q2; nb.y = b.y * q2;
    ((__hip_bfloat162*)(nreps + (size_t)p * ZDIM))[lane] = __float22bfloat162_rn(na);
    ((__hip_bfloat162*)(nreps + (size_t)(p + N_PAIRS) * ZDIM))[lane] = __float22bfloat162_rn(nb);
    if (lane == 0) pos[p] = d * i1 * i2;
}

// Block: 256 thr = 4 waves stacked vertically: wave w owns rows
// [rt*128 + w*32, +32). All waves share the same 64-col B-frags per step
// (dedup in L1). Block tile = 128 rows x 64 cols, swept over 8 steps
// (512-col slab). grid = 64 row-tiles * 16 col-slabs = 1024 blocks
// = 4 blocks/CU resident at 4 waves/SIMD.
__global__ __launch_bounds__(256) void k_simsum(
    const __hip_bfloat16* __restrict__ nreps, float* __restrict__ denom)
{
    const int tid  = threadIdx.x;
    const int lane = tid & 63;
    const int w    = tid >> 6;
    const int rt   = blockIdx.x >> 4;   // row tile [0,64)
    const int cs   = blockIdx.x & 15;   // col slab [0,16)
    const int q    = lane >> 4;         // quad 0..3 (selects k-chunk of 8)
    const int l16  = lane & 15;

    // ---- persistent A fragments: wave's 32 rows x full K=128 (32 VGPRs) ----
    // A-operand layout: A[m = lane&15][k = q*8 + j]; MFMA k-step ks covers
    // source cols [ks*32, ks*32+32).
    const int rowb = rt * 128 + w * 32;                  // + mt*16 (+ l16)
    const __hip_bfloat16* Abase = nreps + (size_t)(rowb + l16) * ZDIM + q * 8;
    bf16x8 afrag[2][4];
    #pragma unroll
    for (int mt = 0; mt < 2; ++mt)
        #pragma unroll
        for (int ks = 0; ks < 4; ++ks)
            afrag[mt][ks] = *(const bf16x8*)(Abase + mt * 16 * ZDIM + ks * 32);

    float rowsum[2][4];
    #pragma unroll
    for (int mt = 0; mt < 2; ++mt)
        #pragma unroll
        for (int r = 0; r < 4; ++r) rowsum[mt][r] = 0.0f;

    for (int it = 0; it < 8; ++it) {
        floatx4 acc[2][4];
        #pragma unroll
        for (int mt = 0; mt < 2; ++mt)
            #pragma unroll
            for (int nt = 0; nt < 4; ++nt) {
                acc[mt][nt].x = 0.f; acc[mt][nt].y = 0.f;
                acc[mt][nt].z = 0.f; acc[mt][nt].w = 0.f;
            }
        // B-operand layout: B[k = q*8 + j][n = lane&15]; row-major source,
        // so B-frag load pattern is identical to A-frag (sim = A * A^T).
        const int colb = cs * 512 + it * 64;             // + nt*16 (+ l16)
        const __hip_bfloat16* Bbase = nreps + (size_t)(colb + l16) * ZDIM + q * 8;
        #pragma unroll
        for (int ks = 0; ks < 4; ++ks) {
            bf16x8 bfrag[4];
            #pragma unroll
            for (int nt = 0; nt < 4; ++nt)
                bfrag[nt] = *(const bf16x8*)(Bbase + nt * 16 * ZDIM + ks * 32);
            #pragma unroll
            for (int mt = 0; mt < 2; ++mt)
                #pragma unroll
                for (int nt = 0; nt < 4; ++nt)
                    acc[mt][nt] = __builtin_amdgcn_mfma_f32_16x16x32_bf16(
                        afrag[mt][ks], bfrag[nt], acc[mt][nt], 0, 0, 0);
        }
        // ---- fused epilogue: bare exp2 + row-sum ----
        // C/D layout: col = lane&15, row = q*4 + reg  (m89/m91 verified)
        // Self-diagonal only possible when the 16x16 tile's row-base ==
        // col-base (wave-uniform compare) -> masked path is rare.
        #pragma unroll
        for (int mt = 0; mt < 2; ++mt) {
            const int rowtb = rowb + mt * 16;
            #pragma unroll
            for (int nt = 0; nt < 4; ++nt) {
                const int coltb = colb + nt * 16;
                if (rowtb == coltb) {
                    #pragma unroll
                    for (int r = 0; r < 4; ++r) {
                        const float e = __builtin_amdgcn_exp2f(acc[mt][nt][r]);
                        rowsum[mt][r] += (l16 == q * 4 + r) ? 0.0f : e;
                    }
                } else {
                    #pragma unroll
                    for (int r = 0; r < 4; ++r)
                        rowsum[mt][r] += __builtin_amdgcn_exp2f(acc[mt][nt][r]);
                }
            }
        }
    }

    // reduce across the 16 lanes holding the same row (cols 0..15 of frag)
    #pragma unroll
    for (int mt = 0; mt < 2; ++mt)
        #pragma unroll
        for (int r = 0; r < 4; ++r) {
            float s = rowsum[mt][r];
            s += __shfl_xor(s, 1, 64);
            s += __shfl_xor(s, 2, 64);
            s += __shfl_xor(s, 4, 64);
            s += __shfl_xor(s, 8, 64);
            rowsum[mt][r] = s;
        }
    if (l16 == 0) {
        #pragma unroll
        for (int mt = 0; mt < 2; ++mt)
            #pragma unroll
            for (int r = 0; r < 4; ++r) {
                const int grow = rowb + mt * 16 + q * 4 + r;
                atomicAdd(&denom[grow], rowsum[mt][r]);
            }
    }
}

__global__ __launch_bounds__(1024) void k_finish(
    const float* __restrict__ denom, const float* __restrict__ pos,
    float* __restrict__ out)
{
    __shared__ float red[1024];
    const int t = threadIdx.x;
    float s = 0.0f;
    for (int i = t; i < NROWS; i += 1024) s += __logf(denom[i]);
    float p = 0.0f;
    for (int i = t; i < N_PAIRS; i += 1024) p += pos[i];
    red[t] = s - 4.0f * p;   // sum_i pos_i/T over 2N rows = 4 * sum_p cos_p
    __syncthreads();
    for (int off = 512; off > 0; off >>= 1) {
        if (t < off) red[t] += red[t + off];
        __syncthreads();
    }
    if (t == 0) out[0] = red[0] / (float)NROWS;
}

extern "C" void kernel_launch(void* const* d_in, const int* in_sizes, int n_in,
                              void* d_out, int out_size, void* d_ws, size_t ws_size,
                              hipStream_t stream) {
    const float* z1 = (const float*)d_in[0];
    const float* z2 = (const float*)d_in[1];
    float* out = (float*)d_out;

    char* ws = (char*)d_ws;
    __hip_bfloat16* nreps = (__hip_bfloat16*)ws;               // 2 MB
    float* denom = (float*)(ws + (size_t)NROWS * ZDIM * 2);    // 32 KB
    float* pos   = denom + NROWS;                              // 16 KB

    k_normalize<<<N_PAIRS / 4, 256, 0, stream>>>(z1, z2, nreps, pos, denom);
    k_simsum<<<1024, 256, 0, stream>>>(nreps, denom);
    k_finish<<<1, 1024, 0, stream>>>(denom, pos, out);
}

// Round 4
// 87.643 us; speedup vs baseline: 1.7783x; 1.4430x over previous
//
#include <hip/hip_runtime.h>
#include <hip/hip_bf16.h>

// NT-Xent loss, N=4096, Z=128, T=0.5.
//
// Key structural idea (round 4): the scratch matrix is stored in
// MFMA-FRAGMENT ORDER, not row-major. Granule layout (16 B granules):
//   pack[(G*4 + ks)*64 + q*16 + n] = rows G*16+n, k in [ks*32+q*8, +8)
// so a wave's A- or B-fragment load for (row/col group G, MFMA step ks) is
//   global_load_dwordx4 at pack + ((G*4+ks)*64 + lane)*8   (1 KB contiguous).
// Round 3 post-mortem: fragment loads from row-major data scatter across 16
// rows x 256 B -> 16 cache segments per VMEM instruction -> latency floor
// (MfmaUtil 9.5%, all pipes idle). Packing moves the scatter to k_normalize's
// stores (fire-and-forget).
//
//  k_normalize: row-normalize z1/z2 (fp32), quantize to bf16 scaled by
//               QS = sqrt(2*log2(e)) (folds 1/T=2 and exp->exp2), write in
//               fragment order; exact fp32 pair-cosines pos[4096]; zero denom.
//  k_simsum:    denom[i] = sum_{j!=i} exp(2*sim_ij) via bf16 MFMA with fused
//               exp2 + row-sum epilogue. No LDS, no barriers. ~100 unified
//               regs (afrag[2][4]=32, acc[2][4]=32, rowsum 8, bfrag 16).
//               (round 2 lesson: never force min-waves near the reg budget.)
//  k_finish:    out = (sum_i log denom_i - 4 * sum_p pos_p) / 8192

#define N_PAIRS 4096
#define ZDIM    128
#define NROWS   8192
#define QS 1.6986437717f   // sqrt(2 * log2(e))

typedef __bf16 bf16x8 __attribute__((ext_vector_type(8)));
typedef float  floatx4 __attribute__((ext_vector_type(4)));

__global__ __launch_bounds__(256) void k_normalize(
    const float* __restrict__ z1, const float* __restrict__ z2,
    __hip_bfloat16* __restrict__ pack, float* __restrict__ pos,
    float* __restrict__ denom)
{
    const int zi = blockIdx.x * 256 + threadIdx.x;   // grid 1024 blocks; 32 zero denom
    if (zi < NROWS) denom[zi] = 0.0f;

    const int w = threadIdx.x >> 6;
    const int lane = threadIdx.x & 63;
    const int p = blockIdx.x * 4 + w;            // pair index, < 4096
    const float2 a = ((const float2*)(z1 + (size_t)p * ZDIM))[lane];
    const float2 b = ((const float2*)(z2 + (size_t)p * ZDIM))[lane];
    float s1 = a.x * a.x + a.y * a.y;
    float s2 = b.x * b.x + b.y * b.y;
    float d  = a.x * b.x + a.y * b.y;
    #pragma unroll
    for (int off = 1; off < 64; off <<= 1) {
        s1 += __shfl_xor(s1, off, 64);
        s2 += __shfl_xor(s2, off, 64);
        d  += __shfl_xor(d,  off, 64);
    }
    const float n1 = fmaxf(sqrtf(s1), 1e-8f);
    const float n2 = fmaxf(sqrtf(s2), 1e-8f);
    const float i1 = 1.0f / n1, i2 = 1.0f / n2;
    const float q1 = i1 * QS, q2 = i2 * QS;
    float2 na; na.x = a.x * q1; na.y = a.y * q1;
    float2 nb; nb.x = b.x * q2; nb.y = b.y * q2;

    // lane holds elements e0=2*lane, e0+1 of its row:
    //   ks = e0>>5 = lane>>4 ; q = (e0>>3)&3 = (lane>>2)&3 ; j = e0&7 = (lane&3)*2
    // pack elem idx for row r: ((r>>4)*4 + ks)*512 + q*128 + (r&15)*8 + j
    const int ks = lane >> 4;
    const int qq = (lane >> 2) & 3;
    const int jj = (lane & 3) * 2;
    const int r1 = p, r2 = p + N_PAIRS;
    const size_t i1e = ((size_t)((r1 >> 4) * 4 + ks)) * 512 + qq * 128 + (r1 & 15) * 8 + jj;
    const size_t i2e = ((size_t)((r2 >> 4) * 4 + ks)) * 512 + qq * 128 + (r2 & 15) * 8 + jj;
    *(__hip_bfloat162*)(pack + i1e) = __float22bfloat162_rn(na);
    *(__hip_bfloat162*)(pack + i2e) = __float22bfloat162_rn(nb);
    if (lane == 0) pos[p] = d * i1 * i2;
}

// Block: 256 thr = 4 waves stacked vertically: wave w owns rows
// [rt*128 + w*32, +32). All waves share the same 64-col B-frags per step
// (16 KB/step, dedup in L1). Block tile = 128 rows x 64 cols, swept over
// 8 steps (512-col slab). grid = 64 row-tiles * 16 col-slabs = 1024 blocks.
__global__ __launch_bounds__(256) void k_simsum(
    const __hip_bfloat16* __restrict__ pack, float* __restrict__ denom)
{
    const int tid  = threadIdx.x;
    const int lane = tid & 63;
    const int w    = tid >> 6;
    const int rt   = blockIdx.x >> 4;   // row tile [0,64)
    const int cs   = blockIdx.x & 15;   // col slab [0,16)
    const int q    = lane >> 4;         // quad 0..3
    const int l16  = lane & 15;

    // ---- persistent A fragments: wave's 32 rows x full K=128 (32 VGPRs) ----
    // fragment-ordered: granule (G*4+ks)*64 + lane, G = rowgroup
    const int rowb = rt * 128 + w * 32;
    const __hip_bfloat16* Abase =
        pack + ((size_t)(rowb >> 4) * 4) * 512 + lane * 8;
    bf16x8 afrag[2][4];
    #pragma unroll
    for (int mt = 0; mt < 2; ++mt)
        #pragma unroll
        for (int ks = 0; ks < 4; ++ks)
            afrag[mt][ks] = *(const bf16x8*)(Abase + mt * 2048 + ks * 512);

    float rowsum[2][4];
    #pragma unroll
    for (int mt = 0; mt < 2; ++mt)
        #pragma unroll
        for (int r = 0; r < 4; ++r) rowsum[mt][r] = 0.0f;

    for (int it = 0; it < 8; ++it) {
        floatx4 acc[2][4];
        #pragma unroll
        for (int mt = 0; mt < 2; ++mt)
            #pragma unroll
            for (int nt = 0; nt < 4; ++nt) {
                acc[mt][nt].x = 0.f; acc[mt][nt].y = 0.f;
                acc[mt][nt].z = 0.f; acc[mt][nt].w = 0.f;
            }
        const int colb = cs * 512 + it * 64;
        const __hip_bfloat16* Bbase =
            pack + ((size_t)(colb >> 4) * 4) * 512 + lane * 8;
        // load ALL 16 B-frags for this step first (coalesced 1 KB each),
        // then run the MFMA batch — maximizes outstanding VMEM.
        bf16x8 bfrag[4][4];   // [nt][ks]
        #pragma unroll
        for (int nt = 0; nt < 4; ++nt)
            #pragma unroll
            for (int ks = 0; ks < 4; ++ks)
                bfrag[nt][ks] = *(const bf16x8*)(Bbase + nt * 2048 + ks * 512);
        #pragma unroll
        for (int ks = 0; ks < 4; ++ks)
            #pragma unroll
            for (int mt = 0; mt < 2; ++mt)
                #pragma unroll
                for (int nt = 0; nt < 4; ++nt)
                    acc[mt][nt] = __builtin_amdgcn_mfma_f32_16x16x32_bf16(
                        afrag[mt][ks], bfrag[nt][ks], acc[mt][nt], 0, 0, 0);
        // ---- fused epilogue: bare exp2 + row-sum ----
        // C/D layout: col = lane&15, row = q*4 + reg  (m89/m91 verified)
        #pragma unroll
        for (int mt = 0; mt < 2; ++mt) {
            const int rowtb = rowb + mt * 16;
            #pragma unroll
            for (int nt = 0; nt < 4; ++nt) {
                const int coltb = colb + nt * 16;
                if (rowtb == coltb) {          // wave-uniform: diagonal tile
                    #pragma unroll
                    for (int r = 0; r < 4; ++r) {
                        const float e = __builtin_amdgcn_exp2f(acc[mt][nt][r]);
                        rowsum[mt][r] += (l16 == q * 4 + r) ? 0.0f : e;
                    }
                } else {
                    #pragma unroll
                    for (int r = 0; r < 4; ++r)
                        rowsum[mt][r] += __builtin_amdgcn_exp2f(acc[mt][nt][r]);
                }
            }
        }
    }

    // reduce across the 16 lanes holding the same row
    #pragma unroll
    for (int mt = 0; mt < 2; ++mt)
        #pragma unroll
        for (int r = 0; r < 4; ++r) {
            float s = rowsum[mt][r];
            s += __shfl_xor(s, 1, 64);
            s += __shfl_xor(s, 2, 64);
            s += __shfl_xor(s, 4, 64);
            s += __shfl_xor(s, 8, 64);
            rowsum[mt][r] = s;
        }
    if (l16 == 0) {
        #pragma unroll
        for (int mt = 0; mt < 2; ++mt)
            #pragma unroll
            for (int r = 0; r < 4; ++r) {
                const int grow = rowb + mt * 16 + q * 4 + r;
                atomicAdd(&denom[grow], rowsum[mt][r]);
            }
    }
}

__global__ __launch_bounds__(1024) void k_finish(
    const float* __restrict__ denom, const float* __restrict__ pos,
    float* __restrict__ out)
{
    __shared__ float red[1024];
    const int t = threadIdx.x;
    float s = 0.0f;
    for (int i = t; i < NROWS; i += 1024) s += __logf(denom[i]);
    float p = 0.0f;
    for (int i = t; i < N_PAIRS; i += 1024) p += pos[i];
    red[t] = s - 4.0f * p;   // sum_i pos_i/T over 2N rows = 4 * sum_p cos_p
    __syncthreads();
    for (int off = 512; off > 0; off >>= 1) {
        if (t < off) red[t] += red[t + off];
        __syncthreads();
    }
    if (t == 0) out[0] = red[0] / (float)NROWS;
}

extern "C" void kernel_launch(void* const* d_in, const int* in_sizes, int n_in,
                              void* d_out, int out_size, void* d_ws, size_t ws_size,
                              hipStream_t stream) {
    const float* z1 = (const float*)d_in[0];
    const float* z2 = (const float*)d_in[1];
    float* out = (float*)d_out;

    char* ws = (char*)d_ws;
    __hip_bfloat16* pack = (__hip_bfloat16*)ws;                // 2 MB
    float* denom = (float*)(ws + (size_t)NROWS * ZDIM * 2);    // 32 KB
    float* pos   = denom + NROWS;                              // 16 KB

    k_normalize<<<N_PAIRS / 4, 256, 0, stream>>>(z1, z2, pack, pos, denom);
    k_simsum<<<1024, 256, 0, stream>>>(pack, denom);
    k_finish<<<1, 1024, 0, stream>>>(denom, pos, out);
}